// Round 2
// baseline (261.690 us; speedup 1.0000x reference)
//
#include <hip/hip_runtime.h>
#include <math.h>

// CRF log-likelihood, B=2048, T=80, L=128 — v10: v9's wave-autonomous
// recurrence + TLP via column replication.
//
// v9 post-mortem: no-barrier in-register chain was correct, but 1024 waves
// = 1 wave/SIMD left 68% of cycles stalled (MfmaUtil 10%, VALUBusy 22%).
// v10 keeps the identical per-wave structure but packs only 2 distinct
// batch rows into the 16 MFMA columns (8x replication, free on the 90%-idle
// matrix pipe) -> 1024 blocks x 2 waves = 2048 waves = 2 waves/SIMD: each
// wave's dependency/memory stalls are filled by its SIMD-mate.
// Register budget: live state = Afr 128 (AGPR) + xc/xn 64 + Bfr 16 + misc
// ~= 240 peak -> fits 256 @ __launch_bounds__(128, 2).
// Also: 4-deep dependent MFMA chain split into 2x2 parallel chains + add
// (halves exposed MFMA latency per step).
//
// Layout (per wave, q = lane>>4, a = lane&15):
//   D (tile mt, reg r) -> state 32q + 4mt + r ; B (tile kk, elem j) ->
//   state 32q + 8kk + j  => next B-frag = pack of own D regs. No LDS, no
//   barrier, no cross-lane in the main loop. Column a -> batch row a&1.
// Renorm every 4 steps, per-row max via shfl_xor {2,4,8,16,32}, delayed
// apply. Meet-in-middle: fwd wave t=1..39, bwd wave t=78..40; combine
// Z = a_39 . (E v_40) via one emission-free MFMA pass + 1KB LDS handoff.

#define CRF_B 2048
#define CRF_T 80
#define CRF_L 128

typedef __attribute__((ext_vector_type(8))) short bf16x8_t;
typedef __attribute__((ext_vector_type(4))) float f32x4_t;

__device__ __forceinline__ int pack_bf16_trunc(float lo, float hi) {
    return (int)((__float_as_uint(lo) >> 16) | (__float_as_uint(hi) & 0xFFFF0000u));
}
__device__ __forceinline__ unsigned short bft(float f) {
    return (unsigned short)(__float_as_uint(f) >> 16);
}

__global__ __launch_bounds__(128, 2) void crf_v10_kernel(
    const float* __restrict__ x,           // [B,T,L]
    const float* __restrict__ trans,       // [L,L]
    const float* __restrict__ start_trans, // [L]
    const float* __restrict__ end_trans,   // [L]
    const int*   __restrict__ y,           // [B,T]
    float* __restrict__ out)               // [B]
{
    const int tid  = threadIdx.x;
    const int w    = tid >> 6;          // 0 = forward wave, 1 = backward wave
    const int lane = tid & 63;
    const int q    = lane >> 4;         // quad: owns states [32q, 32q+32)
    const int a    = lane & 15;         // MFMA n-column; batch row = a & 1
    const int row0 = blockIdx.x * 2;
    const int brow = row0 + (a & 1);

    __shared__ __attribute__((aligned(16))) float u_lds[2][132];
    __shared__ float crunB_lds[2];
    __shared__ float numb[2];

    // ---------------- numerator: wave w -> row row0 + w ----------------
    {
        const int bb = row0 + w;
        const int* yb = y + bb * CRF_T;
        const float* xbn = x + (size_t)bb * CRF_T * CRF_L;
        float p = 0.f;
        for (int t = lane; t < CRF_T; t += 64) {
            const int yt = yb[t];
            p += xbn[t * CRF_L + yt];
            p += (t + 1 < CRF_T) ? trans[yt * CRF_L + yb[t + 1]] : end_trans[yt];
            if (t == 0) p += start_trans[yt];
        }
        #pragma unroll
        for (int off = 1; off <= 32; off <<= 1) p += __shfl_xor(p, off);
        if (lane == 0) numb[w] = p;
    }

    // ---------------- A-fragments: full exp(trans), relabeled ----------------
    // A[m=a][k=8q+j] of tile (mt,kk) = Ê[in_state -> out_state] with
    //   out_state = 32*(a>>2) + 4*mt + (a&3),  in_state = 32*q + 8*kk + j.
    // fwd: Ê = exp(trans[in][out]);  bwd: Ê = exp(trans[out][in]).
    bf16x8_t Afr[8][4];
    {
        const int out_lo = 32 * (a >> 2) + (a & 3);
        const int in_lo  = 32 * q;
        const int so = w ? CRF_L : 1;   // stride of out_s in trans
        const int si = w ? 1 : CRF_L;   // stride of in_s  in trans
        #pragma unroll
        for (int mt = 0; mt < 8; ++mt) {
            const int ob = (out_lo + 4 * mt) * so;
            #pragma unroll
            for (int kk = 0; kk < 4; ++kk) {
                union { bf16x8_t v; unsigned short s[8]; } u;
                #pragma unroll
                for (int j = 0; j < 8; ++j) {
                    const int in_s = in_lo + 8 * kk + j;
                    u.s[j] = bft(__expf(trans[ob + in_s * si]));
                }
                Afr[mt][kk] = u.v;
            }
        }
    }

    const float* xr = x + (size_t)brow * CRF_T * CRF_L;
    int tcur = w ? 78 : 1;
    const int tstep = w ? -1 : 1;

    // ---------------- init: a_0 (fwd) / v_79 (bwd), pack to B-frags ----------------
    float P[8][4];
    bf16x8_t Bfr[4];
    {
        const float* bias = w ? end_trans : start_trans;
        const float* xp = xr + (size_t)(w ? 79 : 0) * CRF_L + 32 * q;
        const float* bp = bias + 32 * q;
        #pragma unroll
        for (int mt = 0; mt < 8; ++mt) {
            const f32x4_t bv = *(const f32x4_t*)&bp[4 * mt];
            const f32x4_t xv = *(const f32x4_t*)&xp[4 * mt];
            #pragma unroll
            for (int r = 0; r < 4; ++r) P[mt][r] = __expf(bv[r] + xv[r]);
        }
        #pragma unroll
        for (int kk = 0; kk < 4; ++kk) {
            union { bf16x8_t v; int wd[4]; } u;
            u.wd[0] = pack_bf16_trunc(P[2 * kk][0],     P[2 * kk][1]);
            u.wd[1] = pack_bf16_trunc(P[2 * kk][2],     P[2 * kk][3]);
            u.wd[2] = pack_bf16_trunc(P[2 * kk + 1][0], P[2 * kk + 1][1]);
            u.wd[3] = pack_bf16_trunc(P[2 * kk + 1][2], P[2 * kk + 1][3]);
            Bfr[kk] = u.v;
        }
    }

    // current emissions
    f32x4_t xc[8], xn[8];
    {
        const float* xp = xr + (size_t)tcur * CRF_L + 32 * q;
        #pragma unroll
        for (int mt = 0; mt < 8; ++mt) xc[mt] = *(const f32x4_t*)&xp[4 * mt];
    }

    float crun = 0.f, inv = 1.f, Mv = 1.f;

    // One recurrence step. MEASURE/APPLY/LAST are literal 0/1 (dead-code
    // eliminated). All array indices compile-time constant (no scratch).
#define CRF_STEP(MEASURE, APPLY, LAST) do {                                     \
        if (!(LAST)) {                                                          \
            const float* xp_ = xr + (size_t)(tcur + tstep) * CRF_L + 32 * q;    \
            _Pragma("unroll")                                                   \
            for (int mt = 0; mt < 8; ++mt) xn[mt] = *(const f32x4_t*)&xp_[4*mt];\
        }                                                                       \
        if (APPLY) { crun += __logf(Mv); inv = __builtin_amdgcn_rcpf(Mv); }     \
        float e_[8][4];                                                         \
        _Pragma("unroll")                                                       \
        for (int mt = 0; mt < 8; ++mt)                                          \
            _Pragma("unroll")                                                   \
            for (int r = 0; r < 4; ++r) {                                       \
                float v_ = __expf(xc[mt][r]);                                   \
                if (APPLY) v_ *= inv;                                           \
                e_[mt][r] = v_;                                                 \
            }                                                                   \
        _Pragma("unroll")                                                       \
        for (int mt = 0; mt < 8; ++mt) {                                        \
            f32x4_t c0 = {0.f, 0.f, 0.f, 0.f};                                  \
            f32x4_t c1 = {0.f, 0.f, 0.f, 0.f};                                  \
            c0 = __builtin_amdgcn_mfma_f32_16x16x32_bf16(Afr[mt][0], Bfr[0],    \
                                                         c0, 0, 0, 0);         \
            c1 = __builtin_amdgcn_mfma_f32_16x16x32_bf16(Afr[mt][1], Bfr[1],    \
                                                         c1, 0, 0, 0);         \
            c0 = __builtin_amdgcn_mfma_f32_16x16x32_bf16(Afr[mt][2], Bfr[2],    \
                                                         c0, 0, 0, 0);         \
            c1 = __builtin_amdgcn_mfma_f32_16x16x32_bf16(Afr[mt][3], Bfr[3],    \
                                                         c1, 0, 0, 0);         \
            _Pragma("unroll")                                                   \
            for (int r = 0; r < 4; ++r)                                         \
                P[mt][r] = (c0[r] + c1[r]) * e_[mt][r];                         \
        }                                                                       \
        _Pragma("unroll")                                                       \
        for (int kk = 0; kk < 4; ++kk) {                                        \
            union { bf16x8_t v; int wd[4]; } u_;                                \
            u_.wd[0] = pack_bf16_trunc(P[2 * kk][0],     P[2 * kk][1]);         \
            u_.wd[1] = pack_bf16_trunc(P[2 * kk][2],     P[2 * kk][3]);         \
            u_.wd[2] = pack_bf16_trunc(P[2 * kk + 1][0], P[2 * kk + 1][1]);     \
            u_.wd[3] = pack_bf16_trunc(P[2 * kk + 1][2], P[2 * kk + 1][3]);     \
            Bfr[kk] = u_.v;                                                     \
        }                                                                       \
        if (MEASURE) {                                                          \
            float g_ = P[0][0];                                                 \
            _Pragma("unroll")                                                   \
            for (int mt = 0; mt < 8; ++mt)                                      \
                _Pragma("unroll")                                               \
                for (int r = 0; r < 4; ++r) g_ = fmaxf(g_, P[mt][r]);           \
            g_ = fmaxf(g_, __shfl_xor(g_, 2));                                  \
            g_ = fmaxf(g_, __shfl_xor(g_, 4));                                  \
            g_ = fmaxf(g_, __shfl_xor(g_, 8));                                  \
            g_ = fmaxf(g_, __shfl_xor(g_, 16));                                 \
            g_ = fmaxf(g_, __shfl_xor(g_, 32));                                 \
            Mv = g_;                                                            \
        }                                                                       \
        if (!(LAST)) {                                                          \
            _Pragma("unroll")                                                   \
            for (int mt = 0; mt < 8; ++mt) xc[mt] = xn[mt];                     \
            tcur += tstep;                                                      \
        }                                                                       \
    } while (0)

    // ---------------- 39 steps: fwd t=1..39, bwd t=78..40 ----------------
    // cadence: measure at k = 4m+3 (3..35), apply at k = 4m+4 (4..36)
    for (int k4 = 0; k4 < 9; ++k4) {
        CRF_STEP(0, 0, 0);   // k = 4m+1
        CRF_STEP(0, 0, 0);   // k = 4m+2
        CRF_STEP(1, 0, 0);   // k = 4m+3: measure
        CRF_STEP(0, 1, 0);   // k = 4m+4: apply
    }
    CRF_STEP(0, 0, 0);       // k = 37
    CRF_STEP(0, 0, 0);       // k = 38
    CRF_STEP(0, 0, 1);       // k = 39 (no prefetch)
#undef CRF_STEP

    // ---------------- combine: Z = a_39 . (E v_40) ----------------
    if (w == 1) {
        // u = E v_40 : one emission-free pass; Afr already holds E in layout
        #pragma unroll
        for (int mt = 0; mt < 8; ++mt) {
            f32x4_t c0 = {0.f, 0.f, 0.f, 0.f};
            f32x4_t c1 = {0.f, 0.f, 0.f, 0.f};
            c0 = __builtin_amdgcn_mfma_f32_16x16x32_bf16(Afr[mt][0], Bfr[0], c0, 0, 0, 0);
            c1 = __builtin_amdgcn_mfma_f32_16x16x32_bf16(Afr[mt][1], Bfr[1], c1, 0, 0, 0);
            c0 = __builtin_amdgcn_mfma_f32_16x16x32_bf16(Afr[mt][2], Bfr[2], c0, 0, 0, 0);
            c1 = __builtin_amdgcn_mfma_f32_16x16x32_bf16(Afr[mt][3], Bfr[3], c1, 0, 0, 0);
            if (a < 2) {    // one replica lane-set per row writes u
                f32x4_t uv;
                #pragma unroll
                for (int r = 0; r < 4; ++r) uv[r] = c0[r] + c1[r];
                *(f32x4_t*)&u_lds[a][32 * q + 4 * mt] = uv;
            }
        }
        if (a < 2 && q == 0) crunB_lds[a] = crun;
    }
    __syncthreads();
    if (w == 0) {
        float s = 0.f;
        #pragma unroll
        for (int mt = 0; mt < 8; ++mt) {
            const f32x4_t uv = *(const f32x4_t*)&u_lds[a & 1][32 * q + 4 * mt];
            #pragma unroll
            for (int r = 0; r < 4; ++r) s += P[mt][r] * uv[r];
        }
        // sum over quads: the 4 q-groups partition the 128 states
        s += __shfl_xor(s, 16);
        s += __shfl_xor(s, 32);
        if (a < 2 && q == 0)
            out[row0 + a] = numb[a] - (crun + crunB_lds[a] + __logf(s));
    }
}

extern "C" void kernel_launch(void* const* d_in, const int* in_sizes, int n_in,
                              void* d_out, int out_size, void* d_ws, size_t ws_size,
                              hipStream_t stream) {
    const float* x     = (const float*)d_in[0];
    const float* trans = (const float*)d_in[1];
    const float* st    = (const float*)d_in[2];
    const float* et    = (const float*)d_in[3];
    const int*   y     = (const int*)d_in[4];
    float* out = (float*)d_out;

    crf_v10_kernel<<<CRF_B / 2, 128, 0, stream>>>(x, trans, st, et, y, out);
}

// Round 3
// 201.559 us; speedup vs baseline: 1.2983x; 1.2983x over previous
//
#include <hip/hip_runtime.h>
#include <math.h>

// CRF log-likelihood, B=2048, T=80, L=128 — v11: v10's 2-waves/SIMD plan
// with a register diet that actually fits 256 unified regs/wave.
//
// v10 post-mortem: live set ~290 regs > 256 -> allocator spilled the
// recurrence state (WRITE_SIZE 16KB -> 67MB, FETCH +71MB of scratch reads),
// 169us. The TLP mechanism was never exercised.
//
// v11 diet (target ~245 regs: Afr 128 -> AGPR, arch ~120):
//   - no e_[] array: exp fused into the post-MFMA multiply (off-chain, the
//     scheduler hoists it over the MFMAs since it only needs prefetched x)
//   - no persistent P[8][4]: per-tile f32x4 transient; renorm max is a
//     running fmax; final combine dot reads the bf16-packed Bfr instead
//   - no xc=xn copies: ping-pong xb0/xb1 chosen by literal macro parity
//   - pack via v_perm_b32 (1 inst per word)
//
// Structure (unchanged from v10): wave-autonomous recurrence, state
// relabeling so quad q owns states [32q,32q+32) in BOTH the MFMA D- and
// B-layouts => next B-frag = pack of own D regs; no LDS/barrier/cross-lane
// in the main loop. 2 batch rows per wave (8x column replication, free on
// the idle MFMA pipe) -> 1024 blocks x 2 waves = 2048 waves = 2 waves/SIMD.
// Meet-in-middle: fwd t=1..39, bwd t=78..40; combine Z = a_39 . (E v_40).

#define CRF_B 2048
#define CRF_T 80
#define CRF_L 128

typedef __attribute__((ext_vector_type(8))) short bf16x8_t;
typedef __attribute__((ext_vector_type(4))) float f32x4_t;

__device__ __forceinline__ unsigned short bft(float f) {
    return (unsigned short)(__float_as_uint(f) >> 16);
}
// pack two f32 -> one dword of 2 bf16 (truncation), lo in bits 15:0
__device__ __forceinline__ int pack2(float lo, float hi) {
    return (int)__builtin_amdgcn_perm(__float_as_uint(hi), __float_as_uint(lo),
                                      0x07060302u);
}

__global__ __launch_bounds__(128, 2) void crf_v11_kernel(
    const float* __restrict__ x,           // [B,T,L]
    const float* __restrict__ trans,       // [L,L]
    const float* __restrict__ start_trans, // [L]
    const float* __restrict__ end_trans,   // [L]
    const int*   __restrict__ y,           // [B,T]
    float* __restrict__ out)               // [B]
{
    const int tid  = threadIdx.x;
    const int w    = tid >> 6;          // 0 = forward wave, 1 = backward wave
    const int lane = tid & 63;
    const int q    = lane >> 4;         // quad: owns states [32q, 32q+32)
    const int a    = lane & 15;         // MFMA n-column; batch row = a & 1
    const int row0 = blockIdx.x * 2;
    const int brow = row0 + (a & 1);

    __shared__ __attribute__((aligned(16))) float u_lds[2][132];
    __shared__ float crunB_lds[2];
    __shared__ float numb[2];

    // ---------------- numerator: wave w -> row row0 + w ----------------
    {
        const int bb = row0 + w;
        const int* yb = y + bb * CRF_T;
        const float* xbn = x + (size_t)bb * CRF_T * CRF_L;
        float p = 0.f;
        for (int t = lane; t < CRF_T; t += 64) {
            const int yt = yb[t];
            p += xbn[t * CRF_L + yt];
            p += (t + 1 < CRF_T) ? trans[yt * CRF_L + yb[t + 1]] : end_trans[yt];
            if (t == 0) p += start_trans[yt];
        }
        #pragma unroll
        for (int off = 1; off <= 32; off <<= 1) p += __shfl_xor(p, off);
        if (lane == 0) numb[w] = p;
    }

    // ---------------- A-fragments: full exp(trans), relabeled ----------------
    // A[m=a][k=8q+j] of tile (mt,kk) = Ê[in_state -> out_state] with
    //   out_state = 32*(a>>2) + 4*mt + (a&3),  in_state = 32*q + 8*kk + j.
    // fwd: Ê = exp(trans[in][out]);  bwd: Ê = exp(trans[out][in]).
    bf16x8_t Afr[8][4];
    {
        const int out_lo = 32 * (a >> 2) + (a & 3);
        const int in_lo  = 32 * q;
        const int so = w ? CRF_L : 1;   // stride of out_s in trans
        const int si = w ? 1 : CRF_L;   // stride of in_s  in trans
        #pragma unroll
        for (int mt = 0; mt < 8; ++mt) {
            const int ob = (out_lo + 4 * mt) * so;
            #pragma unroll
            for (int kk = 0; kk < 4; ++kk) {
                union { bf16x8_t v; unsigned short s[8]; } u;
                #pragma unroll
                for (int j = 0; j < 8; ++j) {
                    const int in_s = in_lo + 8 * kk + j;
                    u.s[j] = bft(__expf(trans[ob + in_s * si]));
                }
                Afr[mt][kk] = u.v;
            }
        }
    }

    const float* xr = x + (size_t)brow * CRF_T * CRF_L;
    int tcur = w ? 78 : 1;
    const int tstep = w ? -1 : 1;

    // ---------------- init: a_0 (fwd) / v_79 (bwd) -> Bfr ----------------
    bf16x8_t Bfr[4];
    {
        const float* bias = w ? end_trans : start_trans;
        const float* xp = xr + (size_t)(w ? 79 : 0) * CRF_L + 32 * q;
        const float* bp = bias + 32 * q;
        #pragma unroll
        for (int kk = 0; kk < 4; ++kk) {
            union { bf16x8_t v; int wd[4]; } u;
            #pragma unroll
            for (int h = 0; h < 2; ++h) {   // two 4-state groups per kk
                const int mt = 2 * kk + h;
                const f32x4_t bv = *(const f32x4_t*)&bp[4 * mt];
                const f32x4_t xv = *(const f32x4_t*)&xp[4 * mt];
                float p0 = __expf(bv[0] + xv[0]);
                float p1 = __expf(bv[1] + xv[1]);
                float p2 = __expf(bv[2] + xv[2]);
                float p3 = __expf(bv[3] + xv[3]);
                u.wd[2 * h + 0] = pack2(p0, p1);
                u.wd[2 * h + 1] = pack2(p2, p3);
            }
            Bfr[kk] = u.v;
        }
    }

    // emission ping-pong buffers (raw f32; exp fused at use)
    f32x4_t xb0[8], xb1[8];
    {
        const float* xp = xr + (size_t)tcur * CRF_L + 32 * q;
        #pragma unroll
        for (int mt = 0; mt < 8; ++mt) xb1[mt] = *(const f32x4_t*)&xp[4 * mt];
    }

    float crun = 0.f, inv = 1.f, Mv = 1.f;

    // One recurrence step. CUR/NXT/MEASURE/APPLY/LAST are literal 0/1; all
    // indices compile-time constant (no scratch).
#define CRF_STEP(CUR, NXT, MEASURE, APPLY, LAST) do {                           \
        if (!(LAST)) {                                                          \
            const float* xp_ = xr + (size_t)(tcur + tstep) * CRF_L + 32 * q;    \
            _Pragma("unroll")                                                   \
            for (int mt = 0; mt < 8; ++mt)                                      \
                xb##NXT[mt] = *(const f32x4_t*)&xp_[4 * mt];                    \
        }                                                                       \
        if (APPLY) { crun += __logf(Mv); inv = __builtin_amdgcn_rcpf(Mv); }     \
        float g_ = 0.f;                                                         \
        int bw_[16];                                                            \
        _Pragma("unroll")                                                       \
        for (int mt = 0; mt < 8; ++mt) {                                        \
            f32x4_t c0 = {0.f, 0.f, 0.f, 0.f};                                  \
            f32x4_t c1 = {0.f, 0.f, 0.f, 0.f};                                  \
            c0 = __builtin_amdgcn_mfma_f32_16x16x32_bf16(Afr[mt][0], Bfr[0],    \
                                                         c0, 0, 0, 0);         \
            c1 = __builtin_amdgcn_mfma_f32_16x16x32_bf16(Afr[mt][1], Bfr[1],    \
                                                         c1, 0, 0, 0);         \
            c0 = __builtin_amdgcn_mfma_f32_16x16x32_bf16(Afr[mt][2], Bfr[2],    \
                                                         c0, 0, 0, 0);         \
            c1 = __builtin_amdgcn_mfma_f32_16x16x32_bf16(Afr[mt][3], Bfr[3],    \
                                                         c1, 0, 0, 0);         \
            f32x4_t p_;                                                         \
            _Pragma("unroll")                                                   \
            for (int r = 0; r < 4; ++r) {                                       \
                float v_ = __expf(xb##CUR[mt][r]);                              \
                if (APPLY) v_ *= inv;                                           \
                p_[r] = (c0[r] + c1[r]) * v_;                                   \
            }                                                                   \
            if (MEASURE)                                                        \
                g_ = fmaxf(g_, fmaxf(fmaxf(p_[0], p_[1]),                       \
                                     fmaxf(p_[2], p_[3])));                     \
            bw_[2 * mt + 0] = pack2(p_[0], p_[1]);                              \
            bw_[2 * mt + 1] = pack2(p_[2], p_[3]);                              \
        }                                                                       \
        _Pragma("unroll")                                                       \
        for (int kk = 0; kk < 4; ++kk) {                                        \
            union { int wd[4]; bf16x8_t v; } u_;                                \
            u_.wd[0] = bw_[4 * kk + 0];                                         \
            u_.wd[1] = bw_[4 * kk + 1];                                         \
            u_.wd[2] = bw_[4 * kk + 2];                                         \
            u_.wd[3] = bw_[4 * kk + 3];                                         \
            Bfr[kk] = u_.v;                                                     \
        }                                                                       \
        if (MEASURE) {                                                          \
            g_ = fmaxf(g_, __shfl_xor(g_, 2));                                  \
            g_ = fmaxf(g_, __shfl_xor(g_, 4));                                  \
            g_ = fmaxf(g_, __shfl_xor(g_, 8));                                  \
            g_ = fmaxf(g_, __shfl_xor(g_, 16));                                 \
            g_ = fmaxf(g_, __shfl_xor(g_, 32));                                 \
            Mv = g_;                                                            \
        }                                                                       \
        if (!(LAST)) tcur += tstep;                                             \
    } while (0)

    // ---------------- 39 steps: fwd t=1..39, bwd t=78..40 ----------------
    // buffer parity = k & 1; measure at k = 4m+3, apply at k = 4m+4
    for (int k4 = 0; k4 < 9; ++k4) {
        CRF_STEP(1, 0, 0, 0, 0);   // k = 4m+1
        CRF_STEP(0, 1, 0, 0, 0);   // k = 4m+2
        CRF_STEP(1, 0, 1, 0, 0);   // k = 4m+3: measure
        CRF_STEP(0, 1, 0, 1, 0);   // k = 4m+4: apply
    }
    CRF_STEP(1, 0, 0, 0, 0);       // k = 37
    CRF_STEP(0, 1, 0, 0, 0);       // k = 38
    CRF_STEP(1, 0, 0, 0, 1);       // k = 39 (no prefetch; pack kept)
#undef CRF_STEP

    // ---------------- combine: Z = a_39 . (E v_40) ----------------
    // Bfr now holds a_39 (fwd wave) / v_40 (bwd wave) in bf16.
    if (w == 1) {
        #pragma unroll
        for (int mt = 0; mt < 8; ++mt) {
            f32x4_t c0 = {0.f, 0.f, 0.f, 0.f};
            f32x4_t c1 = {0.f, 0.f, 0.f, 0.f};
            c0 = __builtin_amdgcn_mfma_f32_16x16x32_bf16(Afr[mt][0], Bfr[0], c0, 0, 0, 0);
            c1 = __builtin_amdgcn_mfma_f32_16x16x32_bf16(Afr[mt][1], Bfr[1], c1, 0, 0, 0);
            c0 = __builtin_amdgcn_mfma_f32_16x16x32_bf16(Afr[mt][2], Bfr[2], c0, 0, 0, 0);
            c1 = __builtin_amdgcn_mfma_f32_16x16x32_bf16(Afr[mt][3], Bfr[3], c1, 0, 0, 0);
            if (a < 2) {    // one replica lane-set per row writes u
                f32x4_t uv;
                #pragma unroll
                for (int r = 0; r < 4; ++r) uv[r] = c0[r] + c1[r];
                *(f32x4_t*)&u_lds[a][32 * q + 4 * mt] = uv;
            }
        }
        if (a < 2 && q == 0) crunB_lds[a] = crun;
    }
    __syncthreads();
    if (w == 0) {
        // a_39 from the bf16 pack; u from LDS. state of Bfr[kk] word wi,
        // half h: 32q + 8kk + 2*wi + h
        float s = 0.f;
        #pragma unroll
        for (int kk = 0; kk < 4; ++kk) {
            union { bf16x8_t v; unsigned int wd[4]; } u_;
            u_.v = Bfr[kk];
            const f32x4_t uv0 = *(const f32x4_t*)&u_lds[a & 1][32 * q + 8 * kk];
            const f32x4_t uv1 = *(const f32x4_t*)&u_lds[a & 1][32 * q + 8 * kk + 4];
            #pragma unroll
            for (int wi = 0; wi < 4; ++wi) {
                const float vlo = __uint_as_float(u_.wd[wi] << 16);
                const float vhi = __uint_as_float(u_.wd[wi] & 0xFFFF0000u);
                const float ulo = (wi < 2) ? uv0[2 * wi]     : uv1[2 * wi - 4];
                const float uhi = (wi < 2) ? uv0[2 * wi + 1] : uv1[2 * wi - 3];
                s += vlo * ulo + vhi * uhi;
            }
        }
        // sum over quads: the 4 q-groups partition the 128 states
        s += __shfl_xor(s, 16);
        s += __shfl_xor(s, 32);
        if (a < 2 && q == 0)
            out[row0 + a] = numb[a] - (crun + crunB_lds[a] + __logf(s));
    }
}

extern "C" void kernel_launch(void* const* d_in, const int* in_sizes, int n_in,
                              void* d_out, int out_size, void* d_ws, size_t ws_size,
                              hipStream_t stream) {
    const float* x     = (const float*)d_in[0];
    const float* trans = (const float*)d_in[1];
    const float* st    = (const float*)d_in[2];
    const float* et    = (const float*)d_in[3];
    const int*   y     = (const int*)d_in[4];
    float* out = (float*)d_out;

    crf_v11_kernel<<<CRF_B / 2, 128, 0, stream>>>(x, trans, st, et, y, out);
}

// Round 4
// 200.423 us; speedup vs baseline: 1.3057x; 1.0057x over previous
//
#include <hip/hip_runtime.h>
#include <math.h>

// CRF log-likelihood, B=2048, T=80, L=128 — v12: v11 grid (2 rows/wave,
// 2048 waves = 2/SIMD) with the latency+VALU fixes the counters demanded.
//
// v11 post-mortem: spills gone, 2/SIMD achieved, but 53% idle. Causes:
//  (1) prefetch distance 1 (slack ~0.5 step < HBM latency) -> vmcnt stall
//      at every step's exp;
//  (2) launch_bounds(128,2) capped regs at 256, forcing the exp-after-MFMA
//      fusion and blocking deeper prefetch. 2/SIMD only needs <=1024
//      regs/wave from the pool -- the cap was unnecessary.
//
// v12:
//  - __launch_bounds__(128, 1): compiler free up to 512; ~290 used; pool
//    2048/SIMD still fits 2 waves/SIMD (grid-limited, as before).
//  - distance-2 prefetch, zero extra buffers: per step, (1) exp ALL of the
//    current x buffer into e_[8][4], (2) reuse the freed buffer as the
//    target for x(t+2) loads, (3) MFMA chains, (4) mul+pack. The waitcnt
//    before exp now covers loads issued ~1.9 steps earlier (~1300 cy).
//  - single 4-deep MFMA chain per tile (8 independent chains give the
//    scheduler ILP): saves 32 v_add/step; VALU throughput is the binding
//    pipe once stalls are filled.
//
// Structure otherwise unchanged: wave-autonomous recurrence via state
// relabeling (quad q owns states [32q,32q+32) in both D- and B-layouts =>
// next B-frag = pack of own D regs; no LDS/barrier/cross-lane in loop),
// 8x column replication (2 batch rows), meet-in-middle fwd t=1..39 /
// bwd t=78..40, combine Z = a_39 . (E v_40) via 1KB LDS handoff.

#define CRF_B 2048
#define CRF_T 80
#define CRF_L 128

typedef __attribute__((ext_vector_type(8))) short bf16x8_t;
typedef __attribute__((ext_vector_type(4))) float f32x4_t;

__device__ __forceinline__ unsigned short bft(float f) {
    return (unsigned short)(__float_as_uint(f) >> 16);
}
// pack two f32 -> one dword of 2 bf16 (truncation), lo in bits 15:0
__device__ __forceinline__ int pack2(float lo, float hi) {
    return (int)__builtin_amdgcn_perm(__float_as_uint(hi), __float_as_uint(lo),
                                      0x07060302u);
}

__global__ __launch_bounds__(128, 1) void crf_v12_kernel(
    const float* __restrict__ x,           // [B,T,L]
    const float* __restrict__ trans,       // [L,L]
    const float* __restrict__ start_trans, // [L]
    const float* __restrict__ end_trans,   // [L]
    const int*   __restrict__ y,           // [B,T]
    float* __restrict__ out)               // [B]
{
    const int tid  = threadIdx.x;
    const int w    = tid >> 6;          // 0 = forward wave, 1 = backward wave
    const int lane = tid & 63;
    const int q    = lane >> 4;         // quad: owns states [32q, 32q+32)
    const int a    = lane & 15;         // MFMA n-column; batch row = a & 1
    const int row0 = blockIdx.x * 2;
    const int brow = row0 + (a & 1);

    __shared__ __attribute__((aligned(16))) float u_lds[2][132];
    __shared__ float crunB_lds[2];
    __shared__ float numb[2];

    // ---------------- numerator: wave w -> row row0 + w ----------------
    {
        const int bb = row0 + w;
        const int* yb = y + bb * CRF_T;
        const float* xbn = x + (size_t)bb * CRF_T * CRF_L;
        float p = 0.f;
        for (int t = lane; t < CRF_T; t += 64) {
            const int yt = yb[t];
            p += xbn[t * CRF_L + yt];
            p += (t + 1 < CRF_T) ? trans[yt * CRF_L + yb[t + 1]] : end_trans[yt];
            if (t == 0) p += start_trans[yt];
        }
        #pragma unroll
        for (int off = 1; off <= 32; off <<= 1) p += __shfl_xor(p, off);
        if (lane == 0) numb[w] = p;
    }

    // ---------------- A-fragments: full exp(trans), relabeled ----------------
    // A[m=a][k=8q+j] of tile (mt,kk) = Ê[in_state -> out_state] with
    //   out_state = 32*(a>>2) + 4*mt + (a&3),  in_state = 32*q + 8*kk + j.
    // fwd: Ê = exp(trans[in][out]);  bwd: Ê = exp(trans[out][in]).
    bf16x8_t Afr[8][4];
    {
        const int out_lo = 32 * (a >> 2) + (a & 3);
        const int in_lo  = 32 * q;
        const int so = w ? CRF_L : 1;   // stride of out_s in trans
        const int si = w ? 1 : CRF_L;   // stride of in_s  in trans
        #pragma unroll
        for (int mt = 0; mt < 8; ++mt) {
            const int ob = (out_lo + 4 * mt) * so;
            #pragma unroll
            for (int kk = 0; kk < 4; ++kk) {
                union { bf16x8_t v; unsigned short s[8]; } u;
                #pragma unroll
                for (int j = 0; j < 8; ++j) {
                    const int in_s = in_lo + 8 * kk + j;
                    u.s[j] = bft(__expf(trans[ob + in_s * si]));
                }
                Afr[mt][kk] = u.v;
            }
        }
    }

    const float* xr = x + (size_t)brow * CRF_T * CRF_L;
    int tcur = w ? 78 : 1;
    const int tstep = w ? -1 : 1;

    // ---------------- init: a_0 (fwd) / v_79 (bwd) -> Bfr ----------------
    bf16x8_t Bfr[4];
    {
        const float* bias = w ? end_trans : start_trans;
        const float* xp = xr + (size_t)(w ? 79 : 0) * CRF_L + 32 * q;
        const float* bp = bias + 32 * q;
        #pragma unroll
        for (int kk = 0; kk < 4; ++kk) {
            union { bf16x8_t v; int wd[4]; } u;
            #pragma unroll
            for (int h = 0; h < 2; ++h) {   // two 4-state groups per kk
                const int mt = 2 * kk + h;
                const f32x4_t bv = *(const f32x4_t*)&bp[4 * mt];
                const f32x4_t xv = *(const f32x4_t*)&xp[4 * mt];
                float p0 = __expf(bv[0] + xv[0]);
                float p1 = __expf(bv[1] + xv[1]);
                float p2 = __expf(bv[2] + xv[2]);
                float p3 = __expf(bv[3] + xv[3]);
                u.wd[2 * h + 0] = pack2(p0, p1);
                u.wd[2 * h + 1] = pack2(p2, p3);
            }
            Bfr[kk] = u.v;
        }
    }

    // emission ping-pong buffers; preload steps 1 and 2 (distance-2 pipe)
    f32x4_t xb0[8], xb1[8];
    {
        const float* xp1 = xr + (size_t)tcur * CRF_L + 32 * q;
        const float* xp2 = xr + (size_t)(tcur + tstep) * CRF_L + 32 * q;
        #pragma unroll
        for (int mt = 0; mt < 8; ++mt) {
            xb1[mt] = *(const f32x4_t*)&xp1[4 * mt];
            xb0[mt] = *(const f32x4_t*)&xp2[4 * mt];
        }
    }

    float crun = 0.f, inv = 1.f, Mv = 1.f;

    // One recurrence step. CUR/MEASURE/APPLY/PF are literal 0/1; all array
    // indices compile-time constant (no scratch).
    // Order: exp (frees xb##CUR) -> prefetch t+2 into xb##CUR -> MFMA ->
    // mul+pack. The waitcnt before exp covers loads issued 2 steps ago.
#define CRF_STEP(CUR, MEASURE, APPLY, PF) do {                                  \
        if (APPLY) { crun += __logf(Mv); inv = __builtin_amdgcn_rcpf(Mv); }     \
        float e_[8][4];                                                         \
        _Pragma("unroll")                                                       \
        for (int mt = 0; mt < 8; ++mt)                                          \
            _Pragma("unroll")                                                   \
            for (int r = 0; r < 4; ++r) {                                       \
                float v_ = __expf(xb##CUR[mt][r]);                              \
                if (APPLY) v_ *= inv;                                           \
                e_[mt][r] = v_;                                                 \
            }                                                                   \
        if (PF) {                                                               \
            const float* xp_ = xr + (size_t)(tcur + 2 * tstep) * CRF_L + 32 * q;\
            _Pragma("unroll")                                                   \
            for (int mt = 0; mt < 8; ++mt)                                      \
                xb##CUR[mt] = *(const f32x4_t*)&xp_[4 * mt];                    \
        }                                                                       \
        float g_ = 0.f;                                                         \
        int bw_[16];                                                            \
        _Pragma("unroll")                                                       \
        for (int mt = 0; mt < 8; ++mt) {                                        \
            f32x4_t c_ = {0.f, 0.f, 0.f, 0.f};                                  \
            c_ = __builtin_amdgcn_mfma_f32_16x16x32_bf16(Afr[mt][0], Bfr[0],    \
                                                         c_, 0, 0, 0);         \
            c_ = __builtin_amdgcn_mfma_f32_16x16x32_bf16(Afr[mt][1], Bfr[1],    \
                                                         c_, 0, 0, 0);         \
            c_ = __builtin_amdgcn_mfma_f32_16x16x32_bf16(Afr[mt][2], Bfr[2],    \
                                                         c_, 0, 0, 0);         \
            c_ = __builtin_amdgcn_mfma_f32_16x16x32_bf16(Afr[mt][3], Bfr[3],    \
                                                         c_, 0, 0, 0);         \
            f32x4_t p_;                                                         \
            _Pragma("unroll")                                                   \
            for (int r = 0; r < 4; ++r) p_[r] = c_[r] * e_[mt][r];              \
            if (MEASURE)                                                        \
                g_ = fmaxf(g_, fmaxf(fmaxf(p_[0], p_[1]),                       \
                                     fmaxf(p_[2], p_[3])));                     \
            bw_[2 * mt + 0] = pack2(p_[0], p_[1]);                              \
            bw_[2 * mt + 1] = pack2(p_[2], p_[3]);                              \
        }                                                                       \
        _Pragma("unroll")                                                       \
        for (int kk = 0; kk < 4; ++kk) {                                        \
            union { int wd[4]; bf16x8_t v; } u_;                                \
            u_.wd[0] = bw_[4 * kk + 0];                                         \
            u_.wd[1] = bw_[4 * kk + 1];                                         \
            u_.wd[2] = bw_[4 * kk + 2];                                         \
            u_.wd[3] = bw_[4 * kk + 3];                                         \
            Bfr[kk] = u_.v;                                                     \
        }                                                                       \
        if (MEASURE) {                                                          \
            g_ = fmaxf(g_, __shfl_xor(g_, 2));                                  \
            g_ = fmaxf(g_, __shfl_xor(g_, 4));                                  \
            g_ = fmaxf(g_, __shfl_xor(g_, 8));                                  \
            g_ = fmaxf(g_, __shfl_xor(g_, 16));                                 \
            g_ = fmaxf(g_, __shfl_xor(g_, 32));                                 \
            Mv = g_;                                                            \
        }                                                                       \
        tcur += tstep;                                                          \
    } while (0)

    // ---------------- 39 steps: fwd t=1..39, bwd t=78..40 ----------------
    // buffer parity = k & 1; measure at k = 4m+3, apply at k = 4m+4;
    // prefetch (t+2) valid for k <= 37.
    for (int k4 = 0; k4 < 9; ++k4) {
        CRF_STEP(1, 0, 0, 1);   // k = 4m+1
        CRF_STEP(0, 0, 0, 1);   // k = 4m+2
        CRF_STEP(1, 1, 0, 1);   // k = 4m+3: measure
        CRF_STEP(0, 0, 1, 1);   // k = 4m+4: apply
    }
    CRF_STEP(1, 0, 0, 1);       // k = 37 (prefetch t=39 / t=40)
    CRF_STEP(0, 0, 0, 0);       // k = 38
    CRF_STEP(1, 0, 0, 0);       // k = 39
#undef CRF_STEP

    // ---------------- combine: Z = a_39 . (E v_40) ----------------
    // Bfr now holds a_39 (fwd wave) / v_40 (bwd wave) in bf16.
    if (w == 1) {
        #pragma unroll
        for (int mt = 0; mt < 8; ++mt) {
            f32x4_t c_ = {0.f, 0.f, 0.f, 0.f};
            c_ = __builtin_amdgcn_mfma_f32_16x16x32_bf16(Afr[mt][0], Bfr[0], c_, 0, 0, 0);
            c_ = __builtin_amdgcn_mfma_f32_16x16x32_bf16(Afr[mt][1], Bfr[1], c_, 0, 0, 0);
            c_ = __builtin_amdgcn_mfma_f32_16x16x32_bf16(Afr[mt][2], Bfr[2], c_, 0, 0, 0);
            c_ = __builtin_amdgcn_mfma_f32_16x16x32_bf16(Afr[mt][3], Bfr[3], c_, 0, 0, 0);
            if (a < 2)      // one replica lane-set per row writes u
                *(f32x4_t*)&u_lds[a][32 * q + 4 * mt] = c_;
        }
        if (a < 2 && q == 0) crunB_lds[a] = crun;
    }
    __syncthreads();
    if (w == 0) {
        // a_39 from the bf16 pack; u from LDS. state of Bfr[kk] word wi,
        // half h: 32q + 8kk + 2*wi + h
        float s = 0.f;
        #pragma unroll
        for (int kk = 0; kk < 4; ++kk) {
            union { bf16x8_t v; unsigned int wd[4]; } u_;
            u_.v = Bfr[kk];
            const f32x4_t uv0 = *(const f32x4_t*)&u_lds[a & 1][32 * q + 8 * kk];
            const f32x4_t uv1 = *(const f32x4_t*)&u_lds[a & 1][32 * q + 8 * kk + 4];
            #pragma unroll
            for (int wi = 0; wi < 4; ++wi) {
                const float vlo = __uint_as_float(u_.wd[wi] << 16);
                const float vhi = __uint_as_float(u_.wd[wi] & 0xFFFF0000u);
                const float ulo = (wi < 2) ? uv0[2 * wi]     : uv1[2 * wi - 4];
                const float uhi = (wi < 2) ? uv0[2 * wi + 1] : uv1[2 * wi - 3];
                s += vlo * ulo + vhi * uhi;
            }
        }
        // sum over quads: the 4 q-groups partition the 128 states
        s += __shfl_xor(s, 16);
        s += __shfl_xor(s, 32);
        if (a < 2 && q == 0)
            out[row0 + a] = numb[a] - (crun + crunB_lds[a] + __logf(s));
    }
}

extern "C" void kernel_launch(void* const* d_in, const int* in_sizes, int n_in,
                              void* d_out, int out_size, void* d_ws, size_t ws_size,
                              hipStream_t stream) {
    const float* x     = (const float*)d_in[0];
    const float* trans = (const float*)d_in[1];
    const float* st    = (const float*)d_in[2];
    const float* et    = (const float*)d_in[3];
    const int*   y     = (const int*)d_in[4];
    float* out = (float*)d_out;

    crf_v12_kernel<<<CRF_B / 2, 128, 0, stream>>>(x, trans, st, et, y, out);
}